// Round 7
// baseline (759.847 us; speedup 1.0000x reference)
//
#include <hip/hip_runtime.h>

#define N_TRACES 128
#define TLEN 32
#define IN_DIM 64
#define HID 128
#define G4 (4 * HID)            // 512 gate rows
#define BATCH (N_TRACES * TLEN) // 4096
#define TPB 16                  // traces per block
#define NBLK (N_TRACES / TPB)   // 8 blocks
#define HPAD 136                // r9-verified LDS h row stride (272 B, 16B-aligned)

typedef float f32x4 __attribute__((ext_vector_type(4)));
typedef __bf16 bf16x8 __attribute__((ext_vector_type(8)));

// ---------- device helpers ----------

__device__ __forceinline__ float fast_sigmoid(float x) {
    return 1.0f / (1.0f + __expf(-x));
}
// tanh(x) = 1 - 2/(e^{2x}+1): stable at both extremes
__device__ __forceinline__ float fast_tanh(float x) {
    return 1.0f - 2.0f / (__expf(2.0f * x) + 1.0f);
}

// ---------- input GEMM: out[M][512] = A[M][64] * W[512][64]^T + b1 + b2 ----------
// (unchanged, verified)

template <int K>
__global__ __launch_bounds__(256) void gemm_bt(
    const float* __restrict__ A,
    const float* __restrict__ W,
    const float* __restrict__ b1,
    const float* __restrict__ b2,
    float* __restrict__ out,
    int Nld)
{
    constexpr int LD = 68;
    __shared__ float At[K][LD];
    __shared__ float Wt[K][LD];

    const int tid = threadIdx.x;
    const int m0 = blockIdx.x * 64;
    const int n0 = blockIdx.y * 64;

    const int rot = tid & 3;
    #pragma unroll
    for (int j = 0; j < K / 16; ++j) {
        const int e = 4 * (tid + 256 * j);
        const int row = e / K;
        const int k = e % K;
        float4 va = *(const float4*)(A + (size_t)(m0 + row) * K + k);
        float4 vw = *(const float4*)(W + (size_t)(n0 + row) * K + k);
        float fa[4] = {va.x, va.y, va.z, va.w};
        float fw[4] = {vw.x, vw.y, vw.z, vw.w};
        #pragma unroll
        for (int ii = 0; ii < 4; ++ii) {
            const int i = (ii + rot) & 3;
            At[k + i][row] = fa[i];
            Wt[k + i][row] = fw[i];
        }
    }
    __syncthreads();

    const int tx = tid & 15;
    const int ty = tid >> 4;
    float acc[4][4] = {};

    #pragma unroll 4
    for (int k = 0; k < K; ++k) {
        float4 a = *(const float4*)&At[k][ty * 4];
        float4 w = *(const float4*)&Wt[k][tx * 4];
        acc[0][0] = fmaf(a.x, w.x, acc[0][0]); acc[0][1] = fmaf(a.x, w.y, acc[0][1]);
        acc[0][2] = fmaf(a.x, w.z, acc[0][2]); acc[0][3] = fmaf(a.x, w.w, acc[0][3]);
        acc[1][0] = fmaf(a.y, w.x, acc[1][0]); acc[1][1] = fmaf(a.y, w.y, acc[1][1]);
        acc[1][2] = fmaf(a.y, w.z, acc[1][2]); acc[1][3] = fmaf(a.y, w.w, acc[1][3]);
        acc[2][0] = fmaf(a.z, w.x, acc[2][0]); acc[2][1] = fmaf(a.z, w.y, acc[2][1]);
        acc[2][2] = fmaf(a.z, w.z, acc[2][2]); acc[2][3] = fmaf(a.z, w.w, acc[2][3]);
        acc[3][0] = fmaf(a.w, w.x, acc[3][0]); acc[3][1] = fmaf(a.w, w.y, acc[3][1]);
        acc[3][2] = fmaf(a.w, w.z, acc[3][2]); acc[3][3] = fmaf(a.w, w.w, acc[3][3]);
    }

    float bb[4];
    #pragma unroll
    for (int j = 0; j < 4; ++j) {
        const int n = n0 + tx * 4 + j;
        bb[j] = b1[n] + b2[n];
    }
    #pragma unroll
    for (int i = 0; i < 4; ++i) {
        const int m = m0 + ty * 4 + i;
        float4 v;
        v.x = acc[i][0] + bb[0]; v.y = acc[i][1] + bb[1];
        v.z = acc[i][2] + bb[2]; v.w = acc[i][3] + bb[3];
        *(float4*)(out + (size_t)m * Nld + n0 + tx * 4) = v;
    }
}

// ---------- MFMA helpers (r9 HW-verified fragment conventions, verbatim) ----------

// Per-wave B-operand fragments: 64 gate rows {u + 128*gi} of a [512][128] f32
// matrix, hi/lo bf16 split. Lane supplies row u = 16w + (lane&15), k-chunk
// 8*(lane>>4) within each 32-wide kc window.
__device__ __forceinline__ void load_wfrag(const float* __restrict__ W, int u, int q,
                                           bf16x8 (&bh)[4][4], bf16x8 (&bl)[4][4])
{
    #pragma unroll
    for (int gi = 0; gi < 4; ++gi) {
        const float* wr = W + (size_t)(u + 128 * gi) * HID + 8 * q;
        #pragma unroll
        for (int kc = 0; kc < 4; ++kc) {
            float4 v0 = *(const float4*)(wr + 32 * kc);
            float4 v1 = *(const float4*)(wr + 32 * kc + 4);
            float f0[4] = {v0.x, v0.y, v0.z, v0.w};
            float f1[4] = {v1.x, v1.y, v1.z, v1.w};
            bf16x8 h, l;
            #pragma unroll
            for (int e = 0; e < 4; ++e) {
                __bf16 t0 = (__bf16)f0[e];
                h[e] = t0; l[e] = (__bf16)(f0[e] - (float)t0);
                __bf16 t1 = (__bf16)f1[e];
                h[4 + e] = t1; l[4 + e] = (__bf16)(f1[e] - (float)t1);
            }
            bh[gi][kc] = h; bl[gi][kc] = l;
        }
    }
}

// acc[gi] += W-tile @ h  (3-term hi/lo: ah*bh + al*bh + ah*bl)
__device__ __forceinline__ void mm3(const bf16x8 (&ah)[4], const bf16x8 (&al)[4],
                                    const bf16x8 (&bh)[4][4], const bf16x8 (&bl)[4][4],
                                    f32x4 (&acc)[4])
{
    #pragma unroll
    for (int gi = 0; gi < 4; ++gi) {
        #pragma unroll
        for (int kc = 0; kc < 4; ++kc) {
            acc[gi] = __builtin_amdgcn_mfma_f32_16x16x32_bf16(ah[kc], bh[gi][kc], acc[gi], 0, 0, 0);
            acc[gi] = __builtin_amdgcn_mfma_f32_16x16x32_bf16(al[kc], bh[gi][kc], acc[gi], 0, 0, 0);
            acc[gi] = __builtin_amdgcn_mfma_f32_16x16x32_bf16(ah[kc], bl[gi][kc], acc[gi], 0, 0, 0);
        }
    }
}

// gate nonlinearity for this lane's 4 traces; pre[gi][r] = full preactivation
__device__ __forceinline__ void gates4(const f32x4 (&pre)[4], float (&c)[4],
                                       float (&hv)[4])
{
    #pragma unroll
    for (int r = 0; r < 4; ++r) {
        const float iv = fast_sigmoid(pre[0][r]);
        const float fv = fast_sigmoid(pre[1][r]);
        const float gv = fast_tanh   (pre[2][r]);
        const float ov = fast_sigmoid(pre[3][r]);
        c[r] = fv * c[r] + iv * gv;
        hv[r] = ov * fast_tanh(c[r]);
    }
}

// ---------- layer-pipelined MFMA kernel (8 blocks x 512 threads = 8 waves) ----------
// r12: ONE barrier loop of TLEN+2 = 34 steps replaces r8's 64 barrier steps +
// 32-iter phase C + phase E. At step t the same waves compute (all on MFMA):
//   h0(t)    = gates(Whh0 @ h0(t-1) + xg0(t))          [t <= 31]
//   xp1(t-1) = Wih1 @ h0(t-1)        (same A-frags!)   [1 <= t <= 32]
//   h1(t-2)  = gates(Whh1 @ h1(t-3) + xp1(t-2) + b1)   [t >= 2]
//   y(t-2)   = Wlin . h1(t-2)  (shfl reduce -> LDS)    [t >= 2]
// xp1 stays IN-LANE (Wih1's D-frag layout == gates1's input layout: gate row
// 128gi+16w+cl, trace 4q+r) — 16-reg carry, no memory round-trip. h0/h1 live
// only in double-buffered LDS (r9-verified [m][HPAD] layout). ZERO global ops
// inside the loop (r9 lesson): y accumulates in LDS, written once at the end.
// Weights: 3 matrices x 32 VGPRs of bf16 frags = 96 regs -> 2 waves/SIMD.

__global__ __launch_bounds__(512, 2) void fused_pipe(
    const float* __restrict__ xproj0, // [4096][512] (incl. both layer-0 biases)
    const float* __restrict__ Whh0,   // [512][128]
    const float* __restrict__ Wih1,   // [512][128]
    const float* __restrict__ bih1,   // [512]
    const float* __restrict__ bhh1,   // [512]
    const float* __restrict__ Whh1,   // [512][128]
    const float* __restrict__ Wlin,   // [128]
    const float* __restrict__ blin,   // [1]
    float* __restrict__ y)            // [4096]
{
    const int b = blockIdx.x;
    const int tid = threadIdx.x;
    const int w = tid >> 6;        // wave 0..7 (owns units 16w..16w+15)
    const int lane = tid & 63;
    const int cl = lane & 15;      // operand-row selector
    const int q = lane >> 4;       // k-chunk selector; D-rows = traces 4q..4q+3
    const int u = 16 * w + cl;     // this lane's hidden unit

    __shared__ __align__(16) __bf16 H0h[2][TPB][HPAD];
    __shared__ __align__(16) __bf16 H0l[2][TPB][HPAD];
    __shared__ __align__(16) __bf16 H1h[2][TPB][HPAD];
    __shared__ __align__(16) __bf16 H1l[2][TPB][HPAD];
    __shared__ float ypart[2][8][TPB]; // [parity][wave][trace]
    __shared__ float yall[TLEN][TPB];

    bf16x8 B0h[4][4], B0l[4][4], BIh[4][4], BIl[4][4], BHh[4][4], BHl[4][4];
    load_wfrag(Whh0, u, q, B0h, B0l);
    load_wfrag(Wih1, u, q, BIh, BIl);
    load_wfrag(Whh1, u, q, BHh, BHl);

    float bi1[4];
    #pragma unroll
    for (int gi = 0; gi < 4; ++gi)
        bi1[gi] = bih1[u + 128 * gi] + bhh1[u + 128 * gi];
    const float wl = Wlin[u];
    const float bl0 = blin[0];

    // xg row base pointers, one per r (global trace = TPB*b + 4q + r)
    const float* xb[4];
    #pragma unroll
    for (int r = 0; r < 4; ++r)
        xb[r] = xproj0 + (size_t)(TPB * b + 4 * q + r) * TLEN * G4 + u;

    float c0[4] = {0.f, 0.f, 0.f, 0.f};
    float c1[4] = {0.f, 0.f, 0.f, 0.f};
    f32x4 xp1p[4];                      // xp1(t-1) in-lane carry
    #pragma unroll
    for (int gi = 0; gi < 4; ++gi) xp1p[gi] = (f32x4){0.f, 0.f, 0.f, 0.f};

    #pragma unroll 1
    for (int t = 0; t < TLEN + 2; ++t) {
        const int rb = (t + 1) & 1;     // buffer written at step t-1
        const int wb = t & 1;           // buffer written this step

        // (1) xg0(t) global loads issued FIRST (L2-hot; consumed after MFMAs)
        f32x4 xg[4];
        if (t <= TLEN - 1) {
            #pragma unroll
            for (int gi = 0; gi < 4; ++gi)
                #pragma unroll
                for (int r = 0; r < 4; ++r)
                    xg[gi][r] = xb[r][(size_t)t * G4 + 128 * gi];
        }

        // (2) A-fragments from LDS (written step t-1)
        bf16x8 a0h[4], a0l[4], a1h[4], a1l[4];
        if (t >= 1 && t <= TLEN) {      // h0(t-1), valid 0..31
            #pragma unroll
            for (int kc = 0; kc < 4; ++kc) {
                a0h[kc] = *(const bf16x8*)&H0h[rb][cl][32 * kc + 8 * q];
                a0l[kc] = *(const bf16x8*)&H0l[rb][cl][32 * kc + 8 * q];
            }
        }
        if (t >= 3) {                   // h1(t-3), valid 0..30
            #pragma unroll
            for (int kc = 0; kc < 4; ++kc) {
                a1h[kc] = *(const bf16x8*)&H1h[rb][cl][32 * kc + 8 * q];
                a1l[kc] = *(const bf16x8*)&H1l[rb][cl][32 * kc + 8 * q];
            }
        }

        // (3) MFMA block: up to 144 MFMA/wave
        f32x4 acc0[4], accI[4], accH[4];
        #pragma unroll
        for (int gi = 0; gi < 4; ++gi) {
            acc0[gi] = (f32x4){0.f, 0.f, 0.f, 0.f};
            accI[gi] = (f32x4){0.f, 0.f, 0.f, 0.f};
            accH[gi] = (f32x4){0.f, 0.f, 0.f, 0.f};
        }
        if (t >= 1 && t <= TLEN - 1) mm3(a0h, a0l, B0h, B0l, acc0); // Whh0@h0(t-1)
        if (t >= 1 && t <= TLEN)     mm3(a0h, a0l, BIh, BIl, accI); // Wih1@h0(t-1)
        if (t >= 3)                  mm3(a1h, a1l, BHh, BHl, accH); // Whh1@h1(t-3)

        // (4) gates0 -> h0(t) (acc0 stays zero at t=0: correct peel)
        if (t <= TLEN - 1) {
            f32x4 pre[4];
            #pragma unroll
            for (int gi = 0; gi < 4; ++gi) pre[gi] = acc0[gi] + xg[gi];
            float hv[4];
            gates4(pre, c0, hv);
            #pragma unroll
            for (int r = 0; r < 4; ++r) {
                const int m = 4 * q + r;
                const __bf16 hb = (__bf16)hv[r];
                H0h[wb][m][u] = hb;
                H0l[wb][m][u] = (__bf16)(hv[r] - (float)hb);
            }
        }

        // (5) gates1 -> h1(t-2) (accH zero at t=2: correct peel)
        float h1v[4] = {0.f, 0.f, 0.f, 0.f};
        if (t >= 2) {
            f32x4 pre[4];
            #pragma unroll
            for (int gi = 0; gi < 4; ++gi) {
                pre[gi] = accH[gi] + xp1p[gi];
                #pragma unroll
                for (int r = 0; r < 4; ++r) pre[gi][r] += bi1[gi];
            }
            gates4(pre, c1, h1v);
            #pragma unroll
            for (int r = 0; r < 4; ++r) {
                const int m = 4 * q + r;
                const __bf16 hb = (__bf16)h1v[r];
                H1h[wb][m][u] = hb;
                H1l[wb][m][u] = (__bf16)(h1v[r] - (float)hb);
            }
        }

        // (6) carry xp1(t-1) for next step's gates1
        if (t >= 1) {
            #pragma unroll
            for (int gi = 0; gi < 4; ++gi) xp1p[gi] = accI[gi];
        }

        // (7) y partials for h1(t-2): reduce over the 16 cl-lanes
        if (t >= 2) {
            #pragma unroll
            for (int r = 0; r < 4; ++r) {
                float p = wl * h1v[r];
                p += __shfl_xor(p, 1);
                p += __shfl_xor(p, 2);
                p += __shfl_xor(p, 4);
                p += __shfl_xor(p, 8);
                if (cl == 0) ypart[wb][w][4 * q + r] = p;
            }
        }

        // (8) combine y(t-3) from last step's wave-partials
        if (t >= 3 && tid < TPB) {
            float sv = 0.f;
            #pragma unroll
            for (int ww = 0; ww < 8; ++ww) sv += ypart[rb][ww][tid];
            yall[t - 3][tid] = sv + bl0;
        }

        __syncthreads();
    }

    // epilogue: y(TLEN-1) from partials written at t = TLEN+1 (parity 1)
    if (tid < TPB) {
        float sv = 0.f;
        #pragma unroll
        for (int ww = 0; ww < 8; ++ww) sv += ypart[(TLEN + 1) & 1][ww][tid];
        yall[TLEN - 1][tid] = sv + bl0;
    }
    __syncthreads();

    // single global write of all outputs
    {
        const int tq = tid >> 4;
        const int m = tid & 15;
        y[(size_t)(TPB * b + m) * TLEN + tq] = yall[tq][m];
    }
}

// ---------- launch ----------

extern "C" void kernel_launch(void* const* d_in, const int* in_sizes, int n_in,
                              void* d_out, int out_size, void* d_ws, size_t ws_size,
                              hipStream_t stream) {
    const float* input = (const float*)d_in[0];  // [4096][64]
    const float* W_ih0 = (const float*)d_in[1];  // [512][64]
    const float* W_hh0 = (const float*)d_in[2];  // [512][128]
    const float* b_ih0 = (const float*)d_in[3];  // [512]
    const float* b_hh0 = (const float*)d_in[4];  // [512]
    const float* W_ih1 = (const float*)d_in[5];  // [512][128]
    const float* W_hh1 = (const float*)d_in[6];  // [512][128]
    const float* b_ih1 = (const float*)d_in[7];  // [512]
    const float* b_hh1 = (const float*)d_in[8];  // [512]
    const float* W_lin = (const float*)d_in[9];  // [1][128]
    const float* b_lin = (const float*)d_in[10]; // [1]
    float* out = (float*)d_out;                  // [4096]

    float* xproj0 = (float*)d_ws; // [4096][512], 8 MB

    dim3 ggrid(BATCH / 64, G4 / 64); // (64, 8)

    // K1: xproj0 = input @ W_ih0^T + b_ih0 + b_hh0 (full-chip GEMM)
    gemm_bt<IN_DIM><<<ggrid, 256, 0, stream>>>(input, W_ih0, b_ih0, b_hh0, xproj0, G4);
    // K2: layer-pipelined MFMA LSTM0 || xp1 || LSTM1 || readout
    fused_pipe<<<NBLK, 512, 0, stream>>>(xproj0, W_hh0, W_ih1, b_ih1, b_hh1,
                                         W_hh1, W_lin, b_lin, out);
}

// Round 9
// 329.170 us; speedup vs baseline: 2.3084x; 2.3084x over previous
//
#include <hip/hip_runtime.h>

#define N_TRACES 128
#define TLEN 32
#define IN_DIM 64
#define HID 128
#define G4 (4 * HID)            // 512 gate rows
#define BATCH (N_TRACES * TLEN) // 4096
#define TPB 16                  // traces per block
#define NBLK (N_TRACES / TPB)   // 8 blocks
#define HPAD 136                // LDS h row stride (272 B, 16B-aligned)

typedef float f32x4 __attribute__((ext_vector_type(4)));
typedef __bf16 bf16x8 __attribute__((ext_vector_type(8)));

// ---------- device helpers ----------

__device__ __forceinline__ float fast_sigmoid(float x) {
    return 1.0f / (1.0f + __expf(-x));
}
// tanh(x) = 1 - 2/(e^{2x}+1): stable at both extremes
__device__ __forceinline__ float fast_tanh(float x) {
    return 1.0f - 2.0f / (__expf(2.0f * x) + 1.0f);
}

// ---------- input GEMM: out[M][512] = A[M][64] * W[512][64]^T + b1 + b2 ----------
// (unchanged, verified)

template <int K>
__global__ __launch_bounds__(256) void gemm_bt(
    const float* __restrict__ A,
    const float* __restrict__ W,
    const float* __restrict__ b1,
    const float* __restrict__ b2,
    float* __restrict__ out,
    int Nld)
{
    constexpr int LD = 68;
    __shared__ float At[K][LD];
    __shared__ float Wt[K][LD];

    const int tid = threadIdx.x;
    const int m0 = blockIdx.x * 64;
    const int n0 = blockIdx.y * 64;

    const int rot = tid & 3;
    #pragma unroll
    for (int j = 0; j < K / 16; ++j) {
        const int e = 4 * (tid + 256 * j);
        const int row = e / K;
        const int k = e % K;
        float4 va = *(const float4*)(A + (size_t)(m0 + row) * K + k);
        float4 vw = *(const float4*)(W + (size_t)(n0 + row) * K + k);
        float fa[4] = {va.x, va.y, va.z, va.w};
        float fw[4] = {vw.x, vw.y, vw.z, vw.w};
        #pragma unroll
        for (int ii = 0; ii < 4; ++ii) {
            const int i = (ii + rot) & 3;
            At[k + i][row] = fa[i];
            Wt[k + i][row] = fw[i];
        }
    }
    __syncthreads();

    const int tx = tid & 15;
    const int ty = tid >> 4;
    float acc[4][4] = {};

    #pragma unroll 4
    for (int k = 0; k < K; ++k) {
        float4 a = *(const float4*)&At[k][ty * 4];
        float4 w = *(const float4*)&Wt[k][tx * 4];
        acc[0][0] = fmaf(a.x, w.x, acc[0][0]); acc[0][1] = fmaf(a.x, w.y, acc[0][1]);
        acc[0][2] = fmaf(a.x, w.z, acc[0][2]); acc[0][3] = fmaf(a.x, w.w, acc[0][3]);
        acc[1][0] = fmaf(a.y, w.x, acc[1][0]); acc[1][1] = fmaf(a.y, w.y, acc[1][1]);
        acc[1][2] = fmaf(a.y, w.z, acc[1][2]); acc[1][3] = fmaf(a.y, w.w, acc[1][3]);
        acc[2][0] = fmaf(a.z, w.x, acc[2][0]); acc[2][1] = fmaf(a.z, w.y, acc[2][1]);
        acc[2][2] = fmaf(a.z, w.z, acc[2][2]); acc[2][3] = fmaf(a.z, w.w, acc[2][3]);
        acc[3][0] = fmaf(a.w, w.x, acc[3][0]); acc[3][1] = fmaf(a.w, w.y, acc[3][1]);
        acc[3][2] = fmaf(a.w, w.z, acc[3][2]); acc[3][3] = fmaf(a.w, w.w, acc[3][3]);
    }

    float bb[4];
    #pragma unroll
    for (int j = 0; j < 4; ++j) {
        const int n = n0 + tx * 4 + j;
        bb[j] = b1[n] + b2[n];
    }
    #pragma unroll
    for (int i = 0; i < 4; ++i) {
        const int m = m0 + ty * 4 + i;
        float4 v;
        v.x = acc[i][0] + bb[0]; v.y = acc[i][1] + bb[1];
        v.z = acc[i][2] + bb[2]; v.w = acc[i][3] + bb[3];
        *(float4*)(out + (size_t)m * Nld + n0 + tx * 4) = v;
    }
}

// ---------- MFMA helpers (r9/r12 HW-verified fragment conventions, verbatim) ----------

__device__ __forceinline__ void load_wfrag(const float* __restrict__ W, int u, int q,
                                           bf16x8 (&bh)[4][4], bf16x8 (&bl)[4][4])
{
    #pragma unroll
    for (int gi = 0; gi < 4; ++gi) {
        const float* wr = W + (size_t)(u + 128 * gi) * HID + 8 * q;
        #pragma unroll
        for (int kc = 0; kc < 4; ++kc) {
            float4 v0 = *(const float4*)(wr + 32 * kc);
            float4 v1 = *(const float4*)(wr + 32 * kc + 4);
            float f0[4] = {v0.x, v0.y, v0.z, v0.w};
            float f1[4] = {v1.x, v1.y, v1.z, v1.w};
            bf16x8 h, l;
            #pragma unroll
            for (int e = 0; e < 4; ++e) {
                __bf16 t0 = (__bf16)f0[e];
                h[e] = t0; l[e] = (__bf16)(f0[e] - (float)t0);
                __bf16 t1 = (__bf16)f1[e];
                h[4 + e] = t1; l[4 + e] = (__bf16)(f1[e] - (float)t1);
            }
            bh[gi][kc] = h; bl[gi][kc] = l;
        }
    }
}

// acc[gi] += W-tile @ h  (3-term hi/lo: ah*bh + al*bh + ah*bl)
__device__ __forceinline__ void mm3(const bf16x8 (&ah)[4], const bf16x8 (&al)[4],
                                    const bf16x8 (&bh)[4][4], const bf16x8 (&bl)[4][4],
                                    f32x4 (&acc)[4])
{
    #pragma unroll
    for (int gi = 0; gi < 4; ++gi) {
        #pragma unroll
        for (int kc = 0; kc < 4; ++kc) {
            acc[gi] = __builtin_amdgcn_mfma_f32_16x16x32_bf16(ah[kc], bh[gi][kc], acc[gi], 0, 0, 0);
            acc[gi] = __builtin_amdgcn_mfma_f32_16x16x32_bf16(al[kc], bh[gi][kc], acc[gi], 0, 0, 0);
            acc[gi] = __builtin_amdgcn_mfma_f32_16x16x32_bf16(ah[kc], bl[gi][kc], acc[gi], 0, 0, 0);
        }
    }
}

// gate nonlinearity for this lane's 4 traces; pre[gi][r] = full preactivation
__device__ __forceinline__ void gates4(const f32x4 (&pre)[4], float (&c)[4],
                                       float (&hv)[4])
{
    #pragma unroll
    for (int r = 0; r < 4; ++r) {
        const float iv = fast_sigmoid(pre[0][r]);
        const float fv = fast_sigmoid(pre[1][r]);
        const float gv = fast_tanh   (pre[2][r]);
        const float ov = fast_sigmoid(pre[3][r]);
        c[r] = fv * c[r] + iv * gv;
        hv[r] = ov * fast_tanh(c[r]);
    }
}

// ---------- 3-phase MFMA kernel (8 blocks x 512 threads, ONE matrix resident) ----------
// r14 = r13 with the prefetch off-by-one FIXED (r13 bug: t=1 consumed xg(0)/
// xp1(0) twice and never consumed xg(1)/xp1(1) — the xgc/xgn double-buffer
// copied xgc at the top instead of xgn). Restored r8's verified pattern:
// body does  xg <- xgn  THEN prefetches xgn <- (t+1). Everything else is
// byte-identical to r13:
//   Loop A (32 barrier steps): h0 recurrence [Whh0 resident]. h0 -> LDS dbuf +
//     DELAYED f32 global archive (stored at the TOP of the next step).
//   Loop C (32 iters, barrier-free): xp1(t) = Wih1 @ h0(t) from the archive.
//   Loop D (32 barrier steps): h1 recurrence [Whh1 resident] + in-pipeline y.
// 48 MFMA/wave/step; gates tail wave-parallel (4 traces/lane).

__global__ __launch_bounds__(512, 2) void fused3(
    const float* __restrict__ xproj0, // [4096][512] (incl. both layer-0 biases)
    const float* __restrict__ Whh0,   // [512][128]
    const float* __restrict__ Wih1,   // [512][128]
    const float* __restrict__ bih1,   // [512]
    const float* __restrict__ bhh1,   // [512]
    const float* __restrict__ Whh1,   // [512][128]
    const float* __restrict__ Wlin,   // [128]
    const float* __restrict__ blin,   // [1]
    float* __restrict__ h0a,          // [NBLK][TLEN][TPB][HID] f32 archive
    float* __restrict__ xp1,          // [NBLK][TLEN][4][HID][TPB] f32
    float* __restrict__ y)            // [4096]
{
    const int b = blockIdx.x;
    const int tid = threadIdx.x;
    const int w = tid >> 6;        // wave 0..7 (owns units 16w..16w+15)
    const int lane = tid & 63;
    const int cl = lane & 15;      // operand-row selector
    const int q = lane >> 4;       // k-chunk selector; D-rows = traces 4q..4q+3
    const int u = 16 * w + cl;     // this lane's hidden unit

    __shared__ __align__(16) __bf16 Hh[2][TPB][HPAD];
    __shared__ __align__(16) __bf16 Hl[2][TPB][HPAD];
    __shared__ float ypart[2][8][TPB]; // [parity][wave][trace]
    __shared__ float yall[TLEN][TPB];

    float* h0b = h0a + (size_t)b * TLEN * TPB * HID;
    float* xpb1 = xp1 + (size_t)b * TLEN * 4 * HID * TPB;

    bf16x8 Bh[4][4], Bl[4][4];

    // ================= Loop A: layer-0 recurrence =================
    load_wfrag(Whh0, u, q, Bh, Bl);

    const float* xb[4];
    #pragma unroll
    for (int r = 0; r < 4; ++r)
        xb[r] = xproj0 + (size_t)(TPB * b + 4 * q + r) * TLEN * G4 + u;

    float c0[4] = {0.f, 0.f, 0.f, 0.f};
    float hprev[4];                 // h0(t-1) pending delayed archive
    f32x4 xgn[4];

    {   // t = 0 peel: h(-1) = 0, gates from xg(0) only
        f32x4 pre[4];
        #pragma unroll
        for (int gi = 0; gi < 4; ++gi)
            #pragma unroll
            for (int r = 0; r < 4; ++r)
                pre[gi][r] = xb[r][128 * gi];
        float hv[4];
        gates4(pre, c0, hv);
        #pragma unroll
        for (int r = 0; r < 4; ++r) {
            const int m = 4 * q + r;
            const __bf16 hb = (__bf16)hv[r];
            Hh[0][m][u] = hb;
            Hl[0][m][u] = (__bf16)(hv[r] - (float)hb);
            hprev[r] = hv[r];
        }
    }
    #pragma unroll
    for (int gi = 0; gi < 4; ++gi)
        #pragma unroll
        for (int r = 0; r < 4; ++r)
            xgn[gi][r] = xb[r][(size_t)G4 + 128 * gi]; // xg(1)
    __syncthreads();

    #pragma unroll 1
    for (int t = 1; t < TLEN; ++t) {
        const int rb = (t + 1) & 1;   // buffer written at t-1
        const int wb = t & 1;

        // delayed archive of h0(t-1): full step to retire before barrier drain
        #pragma unroll
        for (int r = 0; r < 4; ++r)
            h0b[((size_t)(t - 1) * TPB + 4 * q + r) * HID + u] = hprev[r];

        // xg(t) from prefetch register; THEN prefetch xg(t+1)  [r13 bugfix]
        f32x4 xg[4];
        #pragma unroll
        for (int gi = 0; gi < 4; ++gi) xg[gi] = xgn[gi];
        if (t < TLEN - 1) {
            #pragma unroll
            for (int gi = 0; gi < 4; ++gi)
                #pragma unroll
                for (int r = 0; r < 4; ++r)
                    xgn[gi][r] = xb[r][(size_t)(t + 1) * G4 + 128 * gi];
        }

        bf16x8 ah[4], al[4];
        #pragma unroll
        for (int kc = 0; kc < 4; ++kc) {
            ah[kc] = *(const bf16x8*)&Hh[rb][cl][32 * kc + 8 * q];
            al[kc] = *(const bf16x8*)&Hl[rb][cl][32 * kc + 8 * q];
        }
        f32x4 acc[4];
        #pragma unroll
        for (int gi = 0; gi < 4; ++gi) acc[gi] = (f32x4){0.f, 0.f, 0.f, 0.f};
        mm3(ah, al, Bh, Bl, acc);

        f32x4 pre[4];
        #pragma unroll
        for (int gi = 0; gi < 4; ++gi) pre[gi] = acc[gi] + xg[gi];
        float hv[4];
        gates4(pre, c0, hv);
        #pragma unroll
        for (int r = 0; r < 4; ++r) {
            const int m = 4 * q + r;
            const __bf16 hb = (__bf16)hv[r];
            Hh[wb][m][u] = hb;
            Hl[wb][m][u] = (__bf16)(hv[r] - (float)hb);
            hprev[r] = hv[r];
        }
        __syncthreads();
    }
    // final archive h0(31), then make all archives visible block-wide
    #pragma unroll
    for (int r = 0; r < 4; ++r)
        h0b[((size_t)(TLEN - 1) * TPB + 4 * q + r) * HID + u] = hprev[r];
    __syncthreads();

    // ================= Loop C: xp1(t) = Wih1 @ h0(t) (barrier-free) =================
    load_wfrag(Wih1, u, q, Bh, Bl);
    #pragma unroll 1
    for (int t = 0; t < TLEN; ++t) {
        const float* ph = h0b + ((size_t)t * TPB + cl) * HID + 8 * q;
        bf16x8 ah[4], al[4];
        #pragma unroll
        for (int kc = 0; kc < 4; ++kc) {
            f32x4 v0 = *(const f32x4*)(ph + 32 * kc);
            f32x4 v1 = *(const f32x4*)(ph + 32 * kc + 4);
            bf16x8 h, l;
            #pragma unroll
            for (int e = 0; e < 4; ++e) {
                __bf16 t0 = (__bf16)v0[e];
                h[e] = t0; l[e] = (__bf16)(v0[e] - (float)t0);
                __bf16 t1 = (__bf16)v1[e];
                h[4 + e] = t1; l[4 + e] = (__bf16)(v1[e] - (float)t1);
            }
            ah[kc] = h; al[kc] = l;
        }
        f32x4 acc[4];
        #pragma unroll
        for (int gi = 0; gi < 4; ++gi) acc[gi] = (f32x4){0.f, 0.f, 0.f, 0.f};
        mm3(ah, al, Bh, Bl, acc);
        #pragma unroll
        for (int gi = 0; gi < 4; ++gi)
            *(f32x4*)(xpb1 + (((size_t)t * 4 + gi) * HID + u) * TPB + 4 * q) = acc[gi];
    }
    __syncthreads(); // drain xp1 stores before loop D reads

    // ================= Loop D: layer-1 recurrence + y readout =================
    load_wfrag(Whh1, u, q, Bh, Bl);
    float bi1[4];
    #pragma unroll
    for (int gi = 0; gi < 4; ++gi)
        bi1[gi] = bih1[u + 128 * gi] + bhh1[u + 128 * gi];
    const float wlv = Wlin[u];
    const float bl0 = blin[0];

    float c1[4] = {0.f, 0.f, 0.f, 0.f};
    f32x4 xpn[4];

    {   // t = 0 peel: xp1(0) loaded directly
        f32x4 pre[4];
        #pragma unroll
        for (int gi = 0; gi < 4; ++gi) {
            pre[gi] = *(const f32x4*)(xpb1 + ((size_t)gi * HID + u) * TPB + 4 * q);
            #pragma unroll
            for (int r = 0; r < 4; ++r) pre[gi][r] += bi1[gi];
        }
        float hv[4];
        gates4(pre, c1, hv);
        #pragma unroll
        for (int r = 0; r < 4; ++r) {
            const int m = 4 * q + r;
            const __bf16 hb = (__bf16)hv[r];
            Hh[0][m][u] = hb;
            Hl[0][m][u] = (__bf16)(hv[r] - (float)hb);
            float p = wlv * hv[r];
            p += __shfl_xor(p, 1); p += __shfl_xor(p, 2);
            p += __shfl_xor(p, 4); p += __shfl_xor(p, 8);
            if (cl == 0) ypart[0][w][m] = p;
        }
    }
    #pragma unroll
    for (int gi = 0; gi < 4; ++gi)
        xpn[gi] = *(const f32x4*)(xpb1 + (((size_t)4 + gi) * HID + u) * TPB + 4 * q); // xp1(1)
    __syncthreads();

    #pragma unroll 1
    for (int t = 1; t < TLEN; ++t) {
        const int rb = (t + 1) & 1;
        const int wb = t & 1;

        // combine y(t-1) from last step's wave-partials
        if (tid < TPB) {
            float sv = 0.f;
            #pragma unroll
            for (int ww = 0; ww < 8; ++ww) sv += ypart[(t - 1) & 1][ww][tid];
            yall[t - 1][tid] = sv + bl0;
        }

        // xp1(t) from prefetch register; THEN prefetch xp1(t+1)  [r13 bugfix]
        f32x4 xg[4];
        #pragma unroll
        for (int gi = 0; gi < 4; ++gi) xg[gi] = xpn[gi];
        if (t < TLEN - 1) {
            #pragma unroll
            for (int gi = 0; gi < 4; ++gi)
                xpn[gi] = *(const f32x4*)(xpb1 + (((size_t)(t + 1) * 4 + gi) * HID + u) * TPB + 4 * q);
        }

        bf16x8 ah[4], al[4];
        #pragma unroll
        for (int kc = 0; kc < 4; ++kc) {
            ah[kc] = *(const bf16x8*)&Hh[rb][cl][32 * kc + 8 * q];
            al[kc] = *(const bf16x8*)&Hl[rb][cl][32 * kc + 8 * q];
        }
        f32x4 acc[4];
        #pragma unroll
        for (int gi = 0; gi < 4; ++gi) acc[gi] = (f32x4){0.f, 0.f, 0.f, 0.f};
        mm3(ah, al, Bh, Bl, acc);

        f32x4 pre[4];
        #pragma unroll
        for (int gi = 0; gi < 4; ++gi) {
            pre[gi] = acc[gi] + xg[gi];
            #pragma unroll
            for (int r = 0; r < 4; ++r) pre[gi][r] += bi1[gi];
        }
        float hv[4];
        gates4(pre, c1, hv);
        #pragma unroll
        for (int r = 0; r < 4; ++r) {
            const int m = 4 * q + r;
            const __bf16 hb = (__bf16)hv[r];
            Hh[wb][m][u] = hb;
            Hl[wb][m][u] = (__bf16)(hv[r] - (float)hb);
            float p = wlv * hv[r];
            p += __shfl_xor(p, 1); p += __shfl_xor(p, 2);
            p += __shfl_xor(p, 4); p += __shfl_xor(p, 8);
            if (cl == 0) ypart[wb][w][m] = p;
        }
        __syncthreads();
    }

    // epilogue: y(31) partials were written at t=31 (parity 1)
    if (tid < TPB) {
        float sv = 0.f;
        #pragma unroll
        for (int ww = 0; ww < 8; ++ww) sv += ypart[(TLEN - 1) & 1][ww][tid];
        yall[TLEN - 1][tid] = sv + bl0;
    }
    __syncthreads();

    // single coalesced output write
    {
        const int tq = tid >> 4;
        const int m = tid & 15;
        y[(size_t)(TPB * b + m) * TLEN + tq] = yall[tq][m];
    }
}

// ---------- launch ----------

extern "C" void kernel_launch(void* const* d_in, const int* in_sizes, int n_in,
                              void* d_out, int out_size, void* d_ws, size_t ws_size,
                              hipStream_t stream) {
    const float* input = (const float*)d_in[0];  // [4096][64]
    const float* W_ih0 = (const float*)d_in[1];  // [512][64]
    const float* W_hh0 = (const float*)d_in[2];  // [512][128]
    const float* b_ih0 = (const float*)d_in[3];  // [512]
    const float* b_hh0 = (const float*)d_in[4];  // [512]
    const float* W_ih1 = (const float*)d_in[5];  // [512][128]
    const float* W_hh1 = (const float*)d_in[6];  // [512][128]
    const float* b_ih1 = (const float*)d_in[7];  // [512]
    const float* b_hh1 = (const float*)d_in[8];  // [512]
    const float* W_lin = (const float*)d_in[9];  // [1][128]
    const float* b_lin = (const float*)d_in[10]; // [1]
    float* out = (float*)d_out;                  // [4096]

    // workspace map (18 MB used, disjoint)
    float* xproj0 = (float*)d_ws;                                // 8 MB
    float* h0a    = (float*)((char*)d_ws + (size_t)(8 << 20));   // 2 MB
    float* xp1    = (float*)((char*)d_ws + (size_t)(10 << 20));  // 8 MB

    dim3 ggrid(BATCH / 64, G4 / 64); // (64, 8)

    // K1: xproj0 = input @ W_ih0^T + b_ih0 + b_hh0 (full-chip GEMM)
    gemm_bt<IN_DIM><<<ggrid, 256, 0, stream>>>(input, W_ih0, b_ih0, b_hh0, xproj0, G4);
    // K2: 3-phase MFMA LSTM (one weight matrix register-resident per phase)
    fused3<<<NBLK, 512, 0, stream>>>(xproj0, W_hh0, W_ih1, b_ih1, b_hh1,
                                     W_hh1, W_lin, b_lin, h0a, xp1, out);
}

// Round 10
// 153.376 us; speedup vs baseline: 4.9541x; 2.1462x over previous
//
#include <hip/hip_runtime.h>

#define N_TRACES 128
#define TLEN 32
#define IN_DIM 64
#define HID 128
#define G4 (4 * HID)            // 512 gate rows
#define BATCH (N_TRACES * TLEN) // 4096

typedef float f32x4 __attribute__((ext_vector_type(4)));
typedef __bf16 bf16x8 __attribute__((ext_vector_type(8)));

// ---------- device helpers ----------

__device__ __forceinline__ float fast_sigmoid(float x) {
    return 1.0f / (1.0f + __expf(-x));
}
// tanh(x) = 1 - 2/(e^{2x}+1): stable at both extremes
__device__ __forceinline__ float fast_tanh(float x) {
    return 1.0f - 2.0f / (__expf(2.0f * x) + 1.0f);
}
// sum across the 4 lanes of a quad, result in all 4 lanes
__device__ __forceinline__ float quad_reduce(float x) {
    x += __int_as_float(__builtin_amdgcn_update_dpp(
        0, __float_as_int(x), 0xB1 /*quad_perm [1,0,3,2]*/, 0xF, 0xF, true));
    x += __int_as_float(__builtin_amdgcn_update_dpp(
        0, __float_as_int(x), 0x4E /*quad_perm [2,3,0,1]*/, 0xF, 0xF, true));
    return x;
}

// load 4 gate rows {u+128i}, k-slice [32s,32s+32) of a [512][128] matrix.
// Land in AGPRs (unified file) at VGPR~88; pin forbids rematerialization.
__device__ __forceinline__ void load_w(const float* __restrict__ W, int u, int s,
                                       float (&w)[4][32]) {
    #pragma unroll
    for (int i = 0; i < 4; ++i) {
        const float* wr = W + (size_t)(u + 128 * i) * HID + 32 * s;
        #pragma unroll
        for (int j = 0; j < 8; ++j) {
            float4 v = *(const float4*)(wr + 4 * j);
            w[i][4 * j + 0] = v.x; w[i][4 * j + 1] = v.y;
            w[i][4 * j + 2] = v.z; w[i][4 * j + 3] = v.w;
        }
    }
    #pragma unroll
    for (int i = 0; i < 4; ++i)
        #pragma unroll
        for (int j = 0; j < 32; ++j)
            asm volatile("" : "+v"(w[i][j]));
}

// acc[i] += dot(w[i][:], hb[0:32]) ; hb must be 16B aligned
__device__ __forceinline__ void matvec_acc(const float (&w)[4][32],
                                           const float* hb, float (&acc)[4]) {
    #pragma unroll
    for (int j = 0; j < 8; ++j) {
        float4 v = *(const float4*)(hb + 4 * j);
        float hx[4] = {v.x, v.y, v.z, v.w};
        #pragma unroll
        for (int e = 0; e < 4; ++e) {
            #pragma unroll
            for (int i = 0; i < 4; ++i)
                acc[i] = fmaf(w[i][4 * j + e], hx[e], acc[i]);
        }
    }
}

// ---------- MFMA helpers (r9/r12/r14 HW-verified fragment conventions) ----------

__device__ __forceinline__ void load_wfrag(const float* __restrict__ W, int u, int q,
                                           bf16x8 (&bh)[4][4], bf16x8 (&bl)[4][4])
{
    #pragma unroll
    for (int gi = 0; gi < 4; ++gi) {
        const float* wr = W + (size_t)(u + 128 * gi) * HID + 8 * q;
        #pragma unroll
        for (int kc = 0; kc < 4; ++kc) {
            float4 v0 = *(const float4*)(wr + 32 * kc);
            float4 v1 = *(const float4*)(wr + 32 * kc + 4);
            float f0[4] = {v0.x, v0.y, v0.z, v0.w};
            float f1[4] = {v1.x, v1.y, v1.z, v1.w};
            bf16x8 h, l;
            #pragma unroll
            for (int e = 0; e < 4; ++e) {
                __bf16 t0 = (__bf16)f0[e];
                h[e] = t0; l[e] = (__bf16)(f0[e] - (float)t0);
                __bf16 t1 = (__bf16)f1[e];
                h[4 + e] = t1; l[4 + e] = (__bf16)(f1[e] - (float)t1);
            }
            bh[gi][kc] = h; bl[gi][kc] = l;
        }
    }
}

// acc[gi] += W-tile @ h  (3-term hi/lo: ah*bh + al*bh + ah*bl)
__device__ __forceinline__ void mm3(const bf16x8 (&ah)[4], const bf16x8 (&al)[4],
                                    const bf16x8 (&bh)[4][4], const bf16x8 (&bl)[4][4],
                                    f32x4 (&acc)[4])
{
    #pragma unroll
    for (int gi = 0; gi < 4; ++gi) {
        #pragma unroll
        for (int kc = 0; kc < 4; ++kc) {
            acc[gi] = __builtin_amdgcn_mfma_f32_16x16x32_bf16(ah[kc], bh[gi][kc], acc[gi], 0, 0, 0);
            acc[gi] = __builtin_amdgcn_mfma_f32_16x16x32_bf16(al[kc], bh[gi][kc], acc[gi], 0, 0, 0);
            acc[gi] = __builtin_amdgcn_mfma_f32_16x16x32_bf16(ah[kc], bl[gi][kc], acc[gi], 0, 0, 0);
        }
    }
}

// ---------- input GEMM: out[M][512] = A[M][64] * W[512][64]^T + b1 + b2 ----------
// (unchanged, verified)

template <int K>
__global__ __launch_bounds__(256) void gemm_bt(
    const float* __restrict__ A,
    const float* __restrict__ W,
    const float* __restrict__ b1,
    const float* __restrict__ b2,
    float* __restrict__ out,
    int Nld)
{
    constexpr int LD = 68;
    __shared__ float At[K][LD];
    __shared__ float Wt[K][LD];

    const int tid = threadIdx.x;
    const int m0 = blockIdx.x * 64;
    const int n0 = blockIdx.y * 64;

    const int rot = tid & 3;
    #pragma unroll
    for (int j = 0; j < K / 16; ++j) {
        const int e = 4 * (tid + 256 * j);
        const int row = e / K;
        const int k = e % K;
        float4 va = *(const float4*)(A + (size_t)(m0 + row) * K + k);
        float4 vw = *(const float4*)(W + (size_t)(n0 + row) * K + k);
        float fa[4] = {va.x, va.y, va.z, va.w};
        float fw[4] = {vw.x, vw.y, vw.z, vw.w};
        #pragma unroll
        for (int ii = 0; ii < 4; ++ii) {
            const int i = (ii + rot) & 3;
            At[k + i][row] = fa[i];
            Wt[k + i][row] = fw[i];
        }
    }
    __syncthreads();

    const int tx = tid & 15;
    const int ty = tid >> 4;
    float acc[4][4] = {};

    #pragma unroll 4
    for (int k = 0; k < K; ++k) {
        float4 a = *(const float4*)&At[k][ty * 4];
        float4 w = *(const float4*)&Wt[k][tx * 4];
        acc[0][0] = fmaf(a.x, w.x, acc[0][0]); acc[0][1] = fmaf(a.x, w.y, acc[0][1]);
        acc[0][2] = fmaf(a.x, w.z, acc[0][2]); acc[0][3] = fmaf(a.x, w.w, acc[0][3]);
        acc[1][0] = fmaf(a.y, w.x, acc[1][0]); acc[1][1] = fmaf(a.y, w.y, acc[1][1]);
        acc[1][2] = fmaf(a.y, w.z, acc[1][2]); acc[1][3] = fmaf(a.y, w.w, acc[1][3]);
        acc[2][0] = fmaf(a.z, w.x, acc[2][0]); acc[2][1] = fmaf(a.z, w.y, acc[2][1]);
        acc[2][2] = fmaf(a.z, w.z, acc[2][2]); acc[2][3] = fmaf(a.z, w.w, acc[2][3]);
        acc[3][0] = fmaf(a.w, w.x, acc[3][0]); acc[3][1] = fmaf(a.w, w.y, acc[3][1]);
        acc[3][2] = fmaf(a.w, w.z, acc[3][2]); acc[3][3] = fmaf(a.w, w.w, acc[3][3]);
    }

    float bb[4];
    #pragma unroll
    for (int j = 0; j < 4; ++j) {
        const int n = n0 + tx * 4 + j;
        bb[j] = b1[n] + b2[n];
    }
    #pragma unroll
    for (int i = 0; i < 4; ++i) {
        const int m = m0 + ty * 4 + i;
        float4 v;
        v.x = acc[i][0] + bb[0]; v.y = acc[i][1] + bb[1];
        v.z = acc[i][2] + bb[2]; v.w = acc[i][3] + bb[3];
        *(float4*)(out + (size_t)m * Nld + n0 + tx * 4) = v;
    }
}

// ---------- fused per-trace kernel (512 threads, r3 quad structure) ----------
// r15 = r3 (165.3 µs champion: quad layout, LDS-resident xp, xg prefetch,
// t=0 peel) with ONE change: phase C (the barrier-free batched projection
// xp[t] = W_ih1 @ h1(t)) moved from 32 VALU-matvec iterations (~11 µs) to
// MFMA: [32 t-rows x 128] @ [512x128]^T per block, hi/lo bf16 3-term,
// 96 MFMA/wave, weights loaded once into the frag regs (fp32 w[] is dead in
// this phase). A-frags read from the hs rows already in LDS — the +4-word
// pad keeps each 8-float k-chunk contiguous (k=32kc+8q -> word 36kc+8q).
// Phases B/D/E and the gemm are byte-identical to r3.

__global__ __launch_bounds__(512) void fused_trace(
    const float* __restrict__ xproj0, // [4096][512] (incl. both layer-0 biases)
    const float* __restrict__ Whh0,   // [512][128]
    const float* __restrict__ Wih1,   // [512][128]
    const float* __restrict__ bih1,   // [512]
    const float* __restrict__ bhh1,   // [512]
    const float* __restrict__ Whh1,   // [512][128]
    const float* __restrict__ Wlin,   // [128]
    const float* __restrict__ blin,   // [1]
    float* __restrict__ y)            // [4096]
{
    const int trace = blockIdx.x;
    const int tid = threadIdx.x;
    const int u = tid >> 2;
    const int s = tid & 3;
    const int pu = u + 4 * (u >> 5); // padded word index for unit u

    __shared__ float hs[TLEN][140];     // h1 then h2, padded (p(127)=139)
    __shared__ float xp[TLEN * G4];     // 64 KB: xproj0, then overwritten w/ xproj1

    float w[4][32];

    // ===== Preload xproj0 -> LDS (coalesced float4, conflict-free writes) =====
    const float* xpb = xproj0 + (size_t)trace * TLEN * G4;
    #pragma unroll
    for (int j = 0; j < 8; ++j) {
        const int f4 = j * 512 + tid;
        float4 v = *(const float4*)(xpb + 4 * f4);
        *(float4*)(&xp[4 * f4]) = v;
    }
    load_w(Whh0, u, s, w);
    __syncthreads();

    // ===== Phase B: layer-0 recurrence =====
    float xg[4], xgn[4];
    #pragma unroll
    for (int i = 0; i < 4; ++i) xg[i] = xp[128 * i + u];       // t=0 inputs
    #pragma unroll
    for (int i = 0; i < 4; ++i) xgn[i] = xp[G4 + 128 * i + u]; // t=1 inputs

    float c = 0.0f;
    // t=0 peel: no recurrent matvec (h(-1)=0)
    if (s == 0) {
        const float iv = fast_sigmoid(xg[0]);
        const float fv = fast_sigmoid(xg[1]);
        const float gv = fast_tanh(xg[2]);
        const float ov = fast_sigmoid(xg[3]);
        c = fv * c + iv * gv;
        hs[0][pu] = ov * fast_tanh(c);
    }
    __syncthreads();

    #pragma unroll 1
    for (int t = 1; t < TLEN; ++t) {
        #pragma unroll
        for (int i = 0; i < 4; ++i) xg[i] = xgn[i];

        float acc[4] = {0.f, 0.f, 0.f, 0.f};
        matvec_acc(w, &hs[t - 1][36 * s], acc);
        #pragma unroll
        for (int i = 0; i < 4; ++i) acc[i] = quad_reduce(acc[i]);

        if (s == 0) {
            const float iv = fast_sigmoid(acc[0] + xg[0]);
            const float fv = fast_sigmoid(acc[1] + xg[1]);
            const float gv = fast_tanh(acc[2] + xg[2]);
            const float ov = fast_sigmoid(acc[3] + xg[3]);
            c = fv * c + iv * gv;
            hs[t][pu] = ov * fast_tanh(c);
        }
        // prefetch next step's gate inputs (xp read-only in this phase)
        if (t < TLEN - 1) {
            #pragma unroll
            for (int i = 0; i < 4; ++i)
                xgn[i] = xp[(t + 1) * G4 + 128 * i + u];
        }
        __syncthreads();
    }

    // ===== Phase C (MFMA): xp[t] = W_ih1 @ h1(t) + b_ih1 + b_hh1 =====
    // Batched over all 32 t-rows; no per-t barrier. Fragment conventions
    // verified in r9/r12/r14 (A row = lane&15, k-chunk 8*(lane>>4);
    // D: row = 4*(lane>>4)+reg = t-offset, col = lane&15 = B-row/unit).
    {
        const int w8 = tid >> 6;       // wave 0..7
        const int lane = tid & 63;
        const int cl = lane & 15;
        const int q = lane >> 4;
        const int um = 16 * w8 + cl;   // this lane's B-row unit

        bf16x8 Bh[4][4], Bl[4][4];
        load_wfrag(Wih1, um, q, Bh, Bl);
        float bim[4];
        #pragma unroll
        for (int gi = 0; gi < 4; ++gi)
            bim[gi] = bih1[um + 128 * gi] + bhh1[um + 128 * gi];

        #pragma unroll
        for (int mt = 0; mt < 2; ++mt) {
            // A-frags: h1 row t = 16*mt + cl; k = 32*kc + 8*q (+e) lives at
            // padded word 36*kc + 8*q (+e) — contiguous 8 floats per chunk.
            bf16x8 ah[4], al[4];
            #pragma unroll
            for (int kc = 0; kc < 4; ++kc) {
                const float* ph = &hs[16 * mt + cl][36 * kc + 8 * q];
                float4 v0 = *(const float4*)(ph);
                float4 v1 = *(const float4*)(ph + 4);
                float f0[4] = {v0.x, v0.y, v0.z, v0.w};
                float f1[4] = {v1.x, v1.y, v1.z, v1.w};
                bf16x8 hh, ll;
                #pragma unroll
                for (int e = 0; e < 4; ++e) {
                    __bf16 t0 = (__bf16)f0[e];
                    hh[e] = t0; ll[e] = (__bf16)(f0[e] - (float)t0);
                    __bf16 t1 = (__bf16)f1[e];
                    hh[4 + e] = t1; ll[4 + e] = (__bf16)(f1[e] - (float)t1);
                }
                ah[kc] = hh; al[kc] = ll;
            }
            f32x4 acc[4];
            #pragma unroll
            for (int gi = 0; gi < 4; ++gi) acc[gi] = (f32x4){0.f, 0.f, 0.f, 0.f};
            mm3(ah, al, Bh, Bl, acc);
            // write: xp[t][128*gi + um], t = 16*mt + 4*q + r
            #pragma unroll
            for (int gi = 0; gi < 4; ++gi)
                #pragma unroll
                for (int r = 0; r < 4; ++r)
                    xp[(16 * mt + 4 * q + r) * G4 + 128 * gi + um] = acc[gi][r] + bim[gi];
        }
    }
    __syncthreads();

    // ===== Phase D: layer-1 recurrence (h2 overwrites hs) =====
    load_w(Whh1, u, s, w);
    #pragma unroll
    for (int i = 0; i < 4; ++i) xg[i] = xp[128 * i + u];       // t=0 inputs
    #pragma unroll
    for (int i = 0; i < 4; ++i) xgn[i] = xp[G4 + 128 * i + u]; // t=1 inputs

    c = 0.0f;
    // t=0 peel
    if (s == 0) {
        const float iv = fast_sigmoid(xg[0]);
        const float fv = fast_sigmoid(xg[1]);
        const float gv = fast_tanh(xg[2]);
        const float ov = fast_sigmoid(xg[3]);
        c = fv * c + iv * gv;
        hs[0][pu] = ov * fast_tanh(c);
    }
    __syncthreads();

    #pragma unroll 1
    for (int t = 1; t < TLEN; ++t) {
        #pragma unroll
        for (int i = 0; i < 4; ++i) xg[i] = xgn[i];

        float acc[4] = {0.f, 0.f, 0.f, 0.f};
        matvec_acc(w, &hs[t - 1][36 * s], acc);
        #pragma unroll
        for (int i = 0; i < 4; ++i) acc[i] = quad_reduce(acc[i]);

        if (s == 0) {
            const float iv = fast_sigmoid(acc[0] + xg[0]);
            const float fv = fast_sigmoid(acc[1] + xg[1]);
            const float gv = fast_tanh(acc[2] + xg[2]);
            const float ov = fast_sigmoid(acc[3] + xg[3]);
            c = fv * c + iv * gv;
            hs[t][pu] = ov * fast_tanh(c);
        }
        if (t < TLEN - 1) {
            #pragma unroll
            for (int i = 0; i < 4; ++i)
                xgn[i] = xp[(t + 1) * G4 + 128 * i + u];
        }
        __syncthreads();
    }

    // ===== Phase E: y[trace*32+t] = dot(h2(t), W_lin) + b_lin =====
    if (tid < 128) {
        const int tq = tid >> 2;
        const int sq = tid & 3;
        float wl[32];
        #pragma unroll
        for (int j = 0; j < 8; ++j) {
            float4 v = *(const float4*)(Wlin + 32 * sq + 4 * j);
            wl[4 * j + 0] = v.x; wl[4 * j + 1] = v.y;
            wl[4 * j + 2] = v.z; wl[4 * j + 3] = v.w;
        }
        const float* hb = &hs[tq][36 * sq];
        float a = 0.f;
        #pragma unroll
        for (int j = 0; j < 8; ++j) {
            float4 v = *(const float4*)(hb + 4 * j);
            a = fmaf(v.x, wl[4 * j + 0], a);
            a = fmaf(v.y, wl[4 * j + 1], a);
            a = fmaf(v.z, wl[4 * j + 2], a);
            a = fmaf(v.w, wl[4 * j + 3], a);
        }
        a = quad_reduce(a);
        if (sq == 0) y[trace * TLEN + tq] = a + blin[0];
    }
}

// ---------- launch ----------

extern "C" void kernel_launch(void* const* d_in, const int* in_sizes, int n_in,
                              void* d_out, int out_size, void* d_ws, size_t ws_size,
                              hipStream_t stream) {
    const float* input = (const float*)d_in[0];  // [4096][64]
    const float* W_ih0 = (const float*)d_in[1];  // [512][64]
    const float* W_hh0 = (const float*)d_in[2];  // [512][128]
    const float* b_ih0 = (const float*)d_in[3];  // [512]
    const float* b_hh0 = (const float*)d_in[4];  // [512]
    const float* W_ih1 = (const float*)d_in[5];  // [512][128]
    const float* W_hh1 = (const float*)d_in[6];  // [512][128]
    const float* b_ih1 = (const float*)d_in[7];  // [512]
    const float* b_hh1 = (const float*)d_in[8];  // [512]
    const float* W_lin = (const float*)d_in[9];  // [1][128]
    const float* b_lin = (const float*)d_in[10]; // [1]
    float* out = (float*)d_out;                  // [4096]

    float* xproj0 = (float*)d_ws; // [4096][512], 8 MB

    dim3 ggrid(BATCH / 64, G4 / 64); // (64, 8)

    // K1: xproj0 = input @ W_ih0^T + b_ih0 + b_hh0 (full-chip GEMM)
    gemm_bt<IN_DIM><<<ggrid, 256, 0, stream>>>(input, W_ih0, b_ih0, b_hh0, xproj0, G4);
    // K2: fused per-trace LSTM0 -> (MFMA) xproj1 -> LSTM1 -> linear readout
    fused_trace<<<N_TRACES, 512, 0, stream>>>(xproj0, W_hh0, W_ih1, b_ih1, b_hh1,
                                              W_hh1, W_lin, b_lin, out);
}

// Round 11
// 149.452 us; speedup vs baseline: 5.0842x; 1.0263x over previous
//
#include <hip/hip_runtime.h>

#define N_TRACES 128
#define TLEN 32
#define IN_DIM 64
#define HID 128
#define G4 (4 * HID)            // 512 gate rows
#define BATCH (N_TRACES * TLEN) // 4096

typedef float f32x4 __attribute__((ext_vector_type(4)));
typedef __bf16 bf16x8 __attribute__((ext_vector_type(8)));

// ---------- device helpers ----------

__device__ __forceinline__ float fast_sigmoid(float x) {
    return 1.0f / (1.0f + __expf(-x));
}
// tanh(x) = 1 - 2/(e^{2x}+1): stable at both extremes
__device__ __forceinline__ float fast_tanh(float x) {
    return 1.0f - 2.0f / (__expf(2.0f * x) + 1.0f);
}
// sum across the 4 lanes of a quad, result in all 4 lanes
__device__ __forceinline__ float quad_reduce(float x) {
    x += __int_as_float(__builtin_amdgcn_update_dpp(
        0, __float_as_int(x), 0xB1 /*quad_perm [1,0,3,2]*/, 0xF, 0xF, true));
    x += __int_as_float(__builtin_amdgcn_update_dpp(
        0, __float_as_int(x), 0x4E /*quad_perm [2,3,0,1]*/, 0xF, 0xF, true));
    return x;
}

// load 4 gate rows {u+128i}, k-slice [32s,32s+32) of a [512][128] matrix.
// Land in AGPRs (unified file); pin forbids rematerialization.
__device__ __forceinline__ void load_w(const float* __restrict__ W, int u, int s,
                                       float (&w)[4][32]) {
    #pragma unroll
    for (int i = 0; i < 4; ++i) {
        const float* wr = W + (size_t)(u + 128 * i) * HID + 32 * s;
        #pragma unroll
        for (int j = 0; j < 8; ++j) {
            float4 v = *(const float4*)(wr + 4 * j);
            w[i][4 * j + 0] = v.x; w[i][4 * j + 1] = v.y;
            w[i][4 * j + 2] = v.z; w[i][4 * j + 3] = v.w;
        }
    }
    #pragma unroll
    for (int i = 0; i < 4; ++i)
        #pragma unroll
        for (int j = 0; j < 32; ++j)
            asm volatile("" : "+v"(w[i][j]));
}

// acc[i] += dot(w[i][:], hb[0:32]) ; hb must be 16B aligned
__device__ __forceinline__ void matvec_acc(const float (&w)[4][32],
                                           const float* hb, float (&acc)[4]) {
    #pragma unroll
    for (int j = 0; j < 8; ++j) {
        float4 v = *(const float4*)(hb + 4 * j);
        float hx[4] = {v.x, v.y, v.z, v.w};
        #pragma unroll
        for (int e = 0; e < 4; ++e) {
            #pragma unroll
            for (int i = 0; i < 4; ++i)
                acc[i] = fmaf(w[i][4 * j + e], hx[e], acc[i]);
        }
    }
}

// ---------- MFMA helpers (r9/r12/r14/r15 HW-verified fragment conventions) ----------

// hi/lo split of 8 consecutive f32 into one bf16x8 pair
__device__ __forceinline__ void split8(const float* p, bf16x8& h, bf16x8& l) {
    float4 v0 = *(const float4*)(p);
    float4 v1 = *(const float4*)(p + 4);
    float f0[4] = {v0.x, v0.y, v0.z, v0.w};
    float f1[4] = {v1.x, v1.y, v1.z, v1.w};
    #pragma unroll
    for (int e = 0; e < 4; ++e) {
        __bf16 t0 = (__bf16)f0[e];
        h[e] = t0; l[e] = (__bf16)(f0[e] - (float)t0);
        __bf16 t1 = (__bf16)f1[e];
        h[4 + e] = t1; l[4 + e] = (__bf16)(f1[e] - (float)t1);
    }
}

// ---------- single fused kernel (128 blocks x 512 threads) ----------
// r16 = r15 (153.4 µs: quad fp32 recurrences + MFMA phase C) with the input
// GEMM kernel FUSED IN as phase A: each block computes its own trace's
// xp[t][512] = input[32x64] @ W_ih0[512x64]^T + b_ih0 + b_hh0 directly into
// LDS via the same (verified) MFMA fragment pattern as phase C, K=64 (kc<2).
// Kills the separate gemm_bt dispatch, the 8 MB xproj0 HBM round-trip, the
// preload loop, and all workspace use. Everything else byte-identical to r15.

__global__ __launch_bounds__(512) void fused_trace(
    const float* __restrict__ input,  // [4096][64]
    const float* __restrict__ Wih0,   // [512][64]
    const float* __restrict__ bih0,   // [512]
    const float* __restrict__ bhh0,   // [512]
    const float* __restrict__ Whh0,   // [512][128]
    const float* __restrict__ Wih1,   // [512][128]
    const float* __restrict__ bih1,   // [512]
    const float* __restrict__ bhh1,   // [512]
    const float* __restrict__ Whh1,   // [512][128]
    const float* __restrict__ Wlin,   // [128]
    const float* __restrict__ blin,   // [1]
    float* __restrict__ y)            // [4096]
{
    const int trace = blockIdx.x;
    const int tid = threadIdx.x;
    const int u = tid >> 2;
    const int s = tid & 3;
    const int pu = u + 4 * (u >> 5); // padded word index for unit u

    __shared__ float hs[TLEN][140];     // h1 then h2, padded (p(127)=139)
    __shared__ float xp[TLEN * G4];     // 64 KB: xproj0, then overwritten w/ xproj1

    float w[4][32];

    // ===== Phase A (MFMA): xp[t] = input_row(t) @ W_ih0^T + b_ih0 + b_hh0 =====
    // [32 t-rows x 64] @ [512 x 64]^T per block; K=64 -> kc<2. Same fragment
    // conventions as phase C (verified r9/r12/r14/r15).
    {
        const int w8 = tid >> 6;       // wave 0..7
        const int lane = tid & 63;
        const int cl = lane & 15;
        const int q = lane >> 4;
        const int um = 16 * w8 + cl;   // this lane's B-row (gate unit)

        bf16x8 Bh[4][2], Bl[4][2];
        #pragma unroll
        for (int gi = 0; gi < 4; ++gi)
            #pragma unroll
            for (int kc = 0; kc < 2; ++kc)
                split8(Wih0 + (size_t)(um + 128 * gi) * IN_DIM + 32 * kc + 8 * q,
                       Bh[gi][kc], Bl[gi][kc]);
        float bb[4];
        #pragma unroll
        for (int gi = 0; gi < 4; ++gi)
            bb[gi] = bih0[um + 128 * gi] + bhh0[um + 128 * gi];

        #pragma unroll
        for (int mt = 0; mt < 2; ++mt) {
            // A-frags: input row trace*32 + 16*mt + cl, k = 32*kc + 8*q
            bf16x8 ah[2], al[2];
            const float* pr = input + (size_t)(trace * TLEN + 16 * mt + cl) * IN_DIM;
            #pragma unroll
            for (int kc = 0; kc < 2; ++kc)
                split8(pr + 32 * kc + 8 * q, ah[kc], al[kc]);

            f32x4 acc[4];
            #pragma unroll
            for (int gi = 0; gi < 4; ++gi) acc[gi] = (f32x4){0.f, 0.f, 0.f, 0.f};
            #pragma unroll
            for (int gi = 0; gi < 4; ++gi) {
                #pragma unroll
                for (int kc = 0; kc < 2; ++kc) {
                    acc[gi] = __builtin_amdgcn_mfma_f32_16x16x32_bf16(ah[kc], Bh[gi][kc], acc[gi], 0, 0, 0);
                    acc[gi] = __builtin_amdgcn_mfma_f32_16x16x32_bf16(al[kc], Bh[gi][kc], acc[gi], 0, 0, 0);
                    acc[gi] = __builtin_amdgcn_mfma_f32_16x16x32_bf16(ah[kc], Bl[gi][kc], acc[gi], 0, 0, 0);
                }
            }
            // write: xp[t][128*gi + um], t = 16*mt + 4*q + r
            #pragma unroll
            for (int gi = 0; gi < 4; ++gi)
                #pragma unroll
                for (int r = 0; r < 4; ++r)
                    xp[(16 * mt + 4 * q + r) * G4 + 128 * gi + um] = acc[gi][r] + bb[gi];
        }
    }
    load_w(Whh0, u, s, w);
    __syncthreads();

    // ===== Phase B: layer-0 recurrence =====
    float xg[4], xgn[4];
    #pragma unroll
    for (int i = 0; i < 4; ++i) xg[i] = xp[128 * i + u];       // t=0 inputs
    #pragma unroll
    for (int i = 0; i < 4; ++i) xgn[i] = xp[G4 + 128 * i + u]; // t=1 inputs

    float c = 0.0f;
    // t=0 peel: no recurrent matvec (h(-1)=0)
    if (s == 0) {
        const float iv = fast_sigmoid(xg[0]);
        const float fv = fast_sigmoid(xg[1]);
        const float gv = fast_tanh(xg[2]);
        const float ov = fast_sigmoid(xg[3]);
        c = fv * c + iv * gv;
        hs[0][pu] = ov * fast_tanh(c);
    }
    __syncthreads();

    #pragma unroll 1
    for (int t = 1; t < TLEN; ++t) {
        #pragma unroll
        for (int i = 0; i < 4; ++i) xg[i] = xgn[i];

        float acc[4] = {0.f, 0.f, 0.f, 0.f};
        matvec_acc(w, &hs[t - 1][36 * s], acc);
        #pragma unroll
        for (int i = 0; i < 4; ++i) acc[i] = quad_reduce(acc[i]);

        if (s == 0) {
            const float iv = fast_sigmoid(acc[0] + xg[0]);
            const float fv = fast_sigmoid(acc[1] + xg[1]);
            const float gv = fast_tanh(acc[2] + xg[2]);
            const float ov = fast_sigmoid(acc[3] + xg[3]);
            c = fv * c + iv * gv;
            hs[t][pu] = ov * fast_tanh(c);
        }
        // prefetch next step's gate inputs (xp read-only in this phase)
        if (t < TLEN - 1) {
            #pragma unroll
            for (int i = 0; i < 4; ++i)
                xgn[i] = xp[(t + 1) * G4 + 128 * i + u];
        }
        __syncthreads();
    }

    // ===== Phase C (MFMA): xp[t] = W_ih1 @ h1(t) + b_ih1 + b_hh1 =====
    // Batched over all 32 t-rows; no per-t barrier. (r15, verified)
    {
        const int w8 = tid >> 6;       // wave 0..7
        const int lane = tid & 63;
        const int cl = lane & 15;
        const int q = lane >> 4;
        const int um = 16 * w8 + cl;   // this lane's B-row unit

        bf16x8 Bh[4][4], Bl[4][4];
        #pragma unroll
        for (int gi = 0; gi < 4; ++gi)
            #pragma unroll
            for (int kc = 0; kc < 4; ++kc)
                split8(Wih1 + (size_t)(um + 128 * gi) * HID + 32 * kc + 8 * q,
                       Bh[gi][kc], Bl[gi][kc]);
        float bim[4];
        #pragma unroll
        for (int gi = 0; gi < 4; ++gi)
            bim[gi] = bih1[um + 128 * gi] + bhh1[um + 128 * gi];

        #pragma unroll
        for (int mt = 0; mt < 2; ++mt) {
            // A-frags: h1 row t = 16*mt + cl; k = 32*kc + 8*q lives at
            // padded word 36*kc + 8*q — contiguous 8 floats per chunk.
            bf16x8 ah[4], al[4];
            #pragma unroll
            for (int kc = 0; kc < 4; ++kc)
                split8(&hs[16 * mt + cl][36 * kc + 8 * q], ah[kc], al[kc]);

            f32x4 acc[4];
            #pragma unroll
            for (int gi = 0; gi < 4; ++gi) acc[gi] = (f32x4){0.f, 0.f, 0.f, 0.f};
            #pragma unroll
            for (int gi = 0; gi < 4; ++gi) {
                #pragma unroll
                for (int kc = 0; kc < 4; ++kc) {
                    acc[gi] = __builtin_amdgcn_mfma_f32_16x16x32_bf16(ah[kc], Bh[gi][kc], acc[gi], 0, 0, 0);
                    acc[gi] = __builtin_amdgcn_mfma_f32_16x16x32_bf16(al[kc], Bh[gi][kc], acc[gi], 0, 0, 0);
                    acc[gi] = __builtin_amdgcn_mfma_f32_16x16x32_bf16(ah[kc], Bl[gi][kc], acc[gi], 0, 0, 0);
                }
            }
            // write: xp[t][128*gi + um], t = 16*mt + 4*q + r
            #pragma unroll
            for (int gi = 0; gi < 4; ++gi)
                #pragma unroll
                for (int r = 0; r < 4; ++r)
                    xp[(16 * mt + 4 * q + r) * G4 + 128 * gi + um] = acc[gi][r] + bim[gi];
        }
    }
    __syncthreads();

    // ===== Phase D: layer-1 recurrence (h2 overwrites hs) =====
    load_w(Whh1, u, s, w);
    #pragma unroll
    for (int i = 0; i < 4; ++i) xg[i] = xp[128 * i + u];       // t=0 inputs
    #pragma unroll
    for (int i = 0; i < 4; ++i) xgn[i] = xp[G4 + 128 * i + u]; // t=1 inputs

    c = 0.0f;
    // t=0 peel
    if (s == 0) {
        const float iv = fast_sigmoid(xg[0]);
        const float fv = fast_sigmoid(xg[1]);
        const float gv = fast_tanh(xg[2]);
        const float ov = fast_sigmoid(xg[3]);
        c = fv * c + iv * gv;
        hs[0][pu] = ov * fast_tanh(c);
    }
    __syncthreads();

    #pragma unroll 1
    for (int t = 1; t < TLEN; ++t) {
        #pragma unroll
        for (int i = 0; i < 4; ++i) xg[i] = xgn[i];

        float acc[4] = {0.f, 0.f, 0.f, 0.f};
        matvec_acc(w, &hs[t - 1][36 * s], acc);
        #pragma unroll
        for (int i = 0; i < 4; ++i) acc[i] = quad_reduce(acc[i]);

        if (s == 0) {
            const float iv = fast_sigmoid(acc[0] + xg[0]);
            const float fv = fast_sigmoid(acc[1] + xg[1]);
            const float gv = fast_tanh(acc[2] + xg[2]);
            const float ov = fast_sigmoid(acc[3] + xg[3]);
            c = fv * c + iv * gv;
            hs[t][pu] = ov * fast_tanh(c);
        }
        if (t < TLEN - 1) {
            #pragma unroll
            for (int i = 0; i < 4; ++i)
                xgn[i] = xp[(t + 1) * G4 + 128 * i + u];
        }
        __syncthreads();
    }

    // ===== Phase E: y[trace*32+t] = dot(h2(t), W_lin) + b_lin =====
    if (tid < 128) {
        const int tq = tid >> 2;
        const int sq = tid & 3;
        float wl[32];
        #pragma unroll
        for (int j = 0; j < 8; ++j) {
            float4 v = *(const float4*)(Wlin + 32 * sq + 4 * j);
            wl[4 * j + 0] = v.x; wl[4 * j + 1] = v.y;
            wl[4 * j + 2] = v.z; wl[4 * j + 3] = v.w;
        }
        const float* hb = &hs[tq][36 * sq];
        float a = 0.f;
        #pragma unroll
        for (int j = 0; j < 8; ++j) {
            float4 v = *(const float4*)(hb + 4 * j);
            a = fmaf(v.x, wl[4 * j + 0], a);
            a = fmaf(v.y, wl[4 * j + 1], a);
            a = fmaf(v.z, wl[4 * j + 2], a);
            a = fmaf(v.w, wl[4 * j + 3], a);
        }
        a = quad_reduce(a);
        if (sq == 0) y[trace * TLEN + tq] = a + blin[0];
    }
}

// ---------- launch ----------

extern "C" void kernel_launch(void* const* d_in, const int* in_sizes, int n_in,
                              void* d_out, int out_size, void* d_ws, size_t ws_size,
                              hipStream_t stream) {
    const float* input = (const float*)d_in[0];  // [4096][64]
    const float* W_ih0 = (const float*)d_in[1];  // [512][64]
    const float* W_hh0 = (const float*)d_in[2];  // [512][128]
    const float* b_ih0 = (const float*)d_in[3];  // [512]
    const float* b_hh0 = (const float*)d_in[4];  // [512]
    const float* W_ih1 = (const float*)d_in[5];  // [512][128]
    const float* W_hh1 = (const float*)d_in[6];  // [512][128]
    const float* b_ih1 = (const float*)d_in[7];  // [512]
    const float* b_hh1 = (const float*)d_in[8];  // [512]
    const float* W_lin = (const float*)d_in[9];  // [1][128]
    const float* b_lin = (const float*)d_in[10]; // [1]
    float* out = (float*)d_out;                  // [4096]

    // ONE kernel: in-block MFMA input projection -> LSTM0 -> (MFMA) xproj1
    // -> LSTM1 -> linear readout. No workspace, no second dispatch.
    fused_trace<<<N_TRACES, 512, 0, stream>>>(input, W_ih0, b_ih0, b_hh0,
                                              W_hh0, W_ih1, b_ih1, b_hh1,
                                              W_hh1, W_lin, b_lin, out);
}